// Round 1
// baseline (290.860 us; speedup 1.0000x reference)
//
#include <hip/hip_runtime.h>
#include <hip/hip_bf16.h>

namespace {
constexpr int NB = 32;      // batch
constexpr int NN = 2000;    // nodes
constexpr int NE = 64000;   // edges
constexpr int ND = 128;     // feature dim (DIN == DH == 128)

// ---- workspace layout (bytes) ----
constexpr size_t G_BYTES    = (size_t)NB * NN * ND * 4;   // 32,768,000
constexpr size_t OFF_CNT    = G_BYTES;                    // int[NN]   in-degree
constexpr size_t OFF_DINV   = OFF_CNT    + (size_t)NN * 4;
constexpr size_t OFF_WSUM   = OFF_DINV   + (size_t)NN * 4;
constexpr size_t OFF_OFFS   = OFF_WSUM   + (size_t)NN * 4;   // int[2048] CSR offsets
constexpr size_t OFF_CURSOR = OFF_OFFS   + 2048 * 4;
constexpr size_t OFF_CSR    = OFF_CURSOR + (size_t)NN * 4;   // int2[NE] (src, w bits)
constexpr size_t OFF_Y      = OFF_CSR    + (size_t)NE * 8;   // float[NB*ND]
constexpr size_t META_END   = OFF_Y      + (size_t)NB * ND * 4;
constexpr size_t META_BYTES = META_END - G_BYTES;
} // namespace

// ---- setup kernels ----
__global__ void k_deg(const int* __restrict__ dst, int* __restrict__ cnt) {
    int e = blockIdx.x * 256 + threadIdx.x;
    if (e < NE) atomicAdd(&cnt[dst[e]], 1);
}

__global__ void k_dinv(const int* __restrict__ cnt, float* __restrict__ dinv,
                       float* __restrict__ wsum) {
    int n = blockIdx.x * 256 + threadIdx.x;
    if (n < NN) {
        float di = rsqrtf((float)(cnt[n] + 1));   // deg = in_degree + 1 (self loop)
        dinv[n] = di;
        wsum[n] = di * di;                        // self-loop term of wsum
    }
}

__global__ __launch_bounds__(1024) void k_scan(const int* __restrict__ cnt,
                                               int* __restrict__ offs) {
    __shared__ int s[2048];
    int t = threadIdx.x;
    s[t]        = (t < NN) ? cnt[t] : 0;
    s[t + 1024] = (t + 1024 < NN) ? cnt[t + 1024] : 0;
    __syncthreads();
    for (int off = 1; off < 2048; off <<= 1) {
        int v0 = (t >= off) ? s[t - off] : 0;
        int v1 = (t + 1024 >= off) ? s[t + 1024 - off] : 0;
        __syncthreads();
        s[t] += v0;
        s[t + 1024] += v1;
        __syncthreads();
    }
    if (t == 0) offs[0] = 0;
    if (t < NN)        offs[t + 1]        = s[t];          // exclusive scan
    if (t + 1024 < NN) offs[t + 1024 + 1] = s[t + 1024];
}

__global__ void k_fill(const int* __restrict__ src, const int* __restrict__ dst,
                       const float* __restrict__ dinv, const int* __restrict__ offs,
                       int* __restrict__ cursor, float* __restrict__ wsum,
                       int2* __restrict__ csr) {
    int e = blockIdx.x * 256 + threadIdx.x;
    if (e < NE) {
        int s  = src[e];
        int dd = dst[e];
        float w = dinv[s] * dinv[dd];
        atomicAdd(&wsum[s], w);                 // out-edge contribution to wsum
        int p = offs[dd] + atomicAdd(&cursor[dd], 1);
        csr[p] = make_int2(s, __float_as_int(w));
    }
}

// ---- gather: G[b,n,:] = dinv[n]^2 * X[b,n,:] + sum_{e: dst=n} w_e * X[b,src_e,:] ----
__global__ __launch_bounds__(128) void k_gather(const float* __restrict__ X,
                                                const int* __restrict__ offs,
                                                const int2* __restrict__ csr,
                                                const float* __restrict__ dinv,
                                                float* __restrict__ G) {
    constexpr int CH = 8;
    const int d = threadIdx.x;
    const int b = blockIdx.y;
    const float* Xb = X + (size_t)b * NN * ND;
    float* Gb = G + (size_t)b * NN * ND;
    const int nEnd = min(NN, (int)(blockIdx.x + 1) * CH);
    for (int n = blockIdx.x * CH; n < nEnd; n++) {
        float di  = dinv[n];
        float acc = di * di * Xb[(size_t)n * ND + d];
        int j0 = offs[n], j1 = offs[n + 1];
        #pragma unroll 4
        for (int j = j0; j < j1; j++) {
            int2 e = csr[j];
            acc = fmaf(__int_as_float(e.y), Xb[(size_t)e.x * ND + d], acc);
        }
        Gb[(size_t)n * ND + d] = acc;
    }
}

// ---- fused GEMM + relu + weighted node-reduction ----
// x1 = relu(G @ W1 + b1);  y[b,:] += sum_n wsum[n] * x1[b,n,:]
__global__ __launch_bounds__(128) void k_gemm_fused(const float* __restrict__ G,
                                                    const float* __restrict__ W1,
                                                    const float* __restrict__ b1,
                                                    const float* __restrict__ wsum,
                                                    float* __restrict__ y) {
    __shared__ float As[128 * 36];   // A^T: As[k][r], stride 36 (16B-aligned rows)
    __shared__ float yred[128];
    const int tid = threadIdx.x;
    const int b   = blockIdx.y;
    const int n0  = blockIdx.x * 32;

    // stage A tile transposed: thread t reads G[n0+j][t] (coalesced), writes As[t][j]
    const float* Gb = G + ((size_t)b * NN + n0) * ND;
    #pragma unroll
    for (int j = 0; j < 32; j++) {
        float v = (n0 + j < NN) ? Gb[j * ND + tid] : 0.f;
        As[tid * 36 + j] = v;
    }
    yred[tid] = 0.f;
    __syncthreads();

    const int cg = tid & 31;   // col group: cols 4*cg .. 4*cg+3
    const int rg = tid >> 5;   // row group: rows 8*rg .. 8*rg+7
    float acc[8][4];
    #pragma unroll
    for (int i = 0; i < 8; i++)
        #pragma unroll
        for (int c = 0; c < 4; c++) acc[i][c] = 0.f;

    const float4* Wrow = (const float4*)W1 + cg;   // W1[k][4cg..]
    #pragma unroll 4
    for (int k = 0; k < 128; k++) {
        float4 w  = Wrow[k * 32];                         // global (L1/L2-hot)
        float4 a0 = *(const float4*)&As[k * 36 + rg * 8];
        float4 a1 = *(const float4*)&As[k * 36 + rg * 8 + 4];
        float av[8] = {a0.x, a0.y, a0.z, a0.w, a1.x, a1.y, a1.z, a1.w};
        #pragma unroll
        for (int i = 0; i < 8; i++) {
            acc[i][0] = fmaf(av[i], w.x, acc[i][0]);
            acc[i][1] = fmaf(av[i], w.y, acc[i][1]);
            acc[i][2] = fmaf(av[i], w.z, acc[i][2]);
            acc[i][3] = fmaf(av[i], w.w, acc[i][3]);
        }
    }

    // epilogue: relu + weighted reduce over this block's 32 rows
    float4 bias = *((const float4*)b1 + cg);
    float yacc[4] = {0.f, 0.f, 0.f, 0.f};
    #pragma unroll
    for (int i = 0; i < 8; i++) {
        int n = n0 + rg * 8 + i;
        if (n < NN) {
            float wn = wsum[n];
            yacc[0] = fmaf(wn, fmaxf(acc[i][0] + bias.x, 0.f), yacc[0]);
            yacc[1] = fmaf(wn, fmaxf(acc[i][1] + bias.y, 0.f), yacc[1]);
            yacc[2] = fmaf(wn, fmaxf(acc[i][2] + bias.z, 0.f), yacc[2]);
            yacc[3] = fmaf(wn, fmaxf(acc[i][3] + bias.w, 0.f), yacc[3]);
        }
    }
    atomicAdd(&yred[4 * cg + 0], yacc[0]);
    atomicAdd(&yred[4 * cg + 1], yacc[1]);
    atomicAdd(&yred[4 * cg + 2], yacc[2]);
    atomicAdd(&yred[4 * cg + 3], yacc[3]);
    __syncthreads();
    atomicAdd(&y[b * ND + tid], yred[tid]);
}

// ---- out[b,:] = (1/N) * y[b,:] @ W2 + b2 ----
__global__ __launch_bounds__(128) void k_out(const float* __restrict__ y,
                                             const float* __restrict__ W2,
                                             const float* __restrict__ b2,
                                             float* __restrict__ out) {
    __shared__ float ys[128];
    const int b = blockIdx.x;
    const int d = threadIdx.x;
    ys[d] = y[b * ND + d] * (1.f / (float)NN);
    __syncthreads();
    float acc = b2[d];
    #pragma unroll 8
    for (int k = 0; k < 128; k++)
        acc = fmaf(ys[k], W2[k * ND + d], acc);
    out[b * ND + d] = acc;
}

extern "C" void kernel_launch(void* const* d_in, const int* in_sizes, int n_in,
                              void* d_out, int out_size, void* d_ws, size_t ws_size,
                              hipStream_t stream) {
    (void)in_sizes; (void)n_in; (void)out_size; (void)ws_size;
    const float* X   = (const float*)d_in[0];   // gene_emb [B,N,128] fp32
    const int*   src = (const int*)d_in[1];     // edge_src [E]
    const int*   dst = (const int*)d_in[2];     // edge_dst [E]
    const float* W1  = (const float*)d_in[3];
    const float* b1  = (const float*)d_in[4];
    const float* W2  = (const float*)d_in[5];
    const float* b2  = (const float*)d_in[6];
    float* out = (float*)d_out;

    char* ws = (char*)d_ws;
    float* G      = (float*)(ws);
    int*   cnt    = (int*)  (ws + OFF_CNT);
    float* dinv   = (float*)(ws + OFF_DINV);
    float* wsum   = (float*)(ws + OFF_WSUM);
    int*   offs   = (int*)  (ws + OFF_OFFS);
    int*   cursor = (int*)  (ws + OFF_CURSOR);
    int2*  csr    = (int2*) (ws + OFF_CSR);
    float* y      = (float*)(ws + OFF_Y);

    // zero the metadata region (cnt, cursor, y; dinv/wsum/offs/csr are overwritten)
    hipMemsetAsync(ws + G_BYTES, 0, META_BYTES, stream);

    k_deg <<<(NE + 255) / 256, 256, 0, stream>>>(dst, cnt);
    k_dinv<<<(NN + 255) / 256, 256, 0, stream>>>(cnt, dinv, wsum);
    k_scan<<<1, 1024, 0, stream>>>(cnt, offs);
    k_fill<<<(NE + 255) / 256, 256, 0, stream>>>(src, dst, dinv, offs, cursor, wsum, csr);

    k_gather<<<dim3(NN / 8, NB), 128, 0, stream>>>(X, offs, csr, dinv, G);
    k_gemm_fused<<<dim3((NN + 31) / 32, NB), 128, 0, stream>>>(G, W1, b1, wsum, y);
    k_out<<<NB, 128, 0, stream>>>(y, W2, b2, out);
}

// Round 2
// 252.498 us; speedup vs baseline: 1.1519x; 1.1519x over previous
//
#include <hip/hip_runtime.h>
#include <hip/hip_bf16.h>

namespace {
constexpr int NB = 32;      // batch
constexpr int NN = 2000;    // nodes
constexpr int NE = 64000;   // edges
constexpr int ND = 128;     // feature dim (DIN == DH == 128)
constexpr int NCHUNK = 63;  // ceil(2000/32) node tiles per batch
constexpr int NXCD = 8;
constexpr int BPX = NB / NXCD;  // batches per XCD = 4

// ---- workspace layout (bytes) ----
constexpr size_t OFF_CNT    = 0;                            // int[NN] in-degree
constexpr size_t OFF_DINV   = OFF_CNT    + (size_t)NN * 4;
constexpr size_t OFF_WSUM   = OFF_DINV   + (size_t)NN * 4;
constexpr size_t OFF_OFFS   = OFF_WSUM   + (size_t)NN * 4;  // int[2048] CSR offsets
constexpr size_t OFF_CURSOR = OFF_OFFS   + 2048 * 4;
constexpr size_t OFF_CSR    = OFF_CURSOR + (size_t)NN * 4;  // int2[NE] (src, w bits)
constexpr size_t OFF_Y      = OFF_CSR    + (size_t)NE * 8;  // float[NB*ND]
constexpr size_t META_END   = OFF_Y      + (size_t)NB * ND * 4;
} // namespace

// ---- setup kernels ----
__global__ void k_deg(const int* __restrict__ dst, int* __restrict__ cnt) {
    int e = blockIdx.x * 256 + threadIdx.x;
    if (e < NE) atomicAdd(&cnt[dst[e]], 1);
}

__global__ void k_dinv(const int* __restrict__ cnt, float* __restrict__ dinv,
                       float* __restrict__ wsum) {
    int n = blockIdx.x * 256 + threadIdx.x;
    if (n < NN) {
        float di = rsqrtf((float)(cnt[n] + 1));   // deg = in_degree + 1 (self loop)
        dinv[n] = di;
        wsum[n] = di * di;                        // self-loop term of wsum
    }
}

__global__ __launch_bounds__(1024) void k_scan(const int* __restrict__ cnt,
                                               int* __restrict__ offs) {
    __shared__ int s[2048];
    int t = threadIdx.x;
    s[t]        = (t < NN) ? cnt[t] : 0;
    s[t + 1024] = (t + 1024 < NN) ? cnt[t + 1024] : 0;
    __syncthreads();
    for (int off = 1; off < 2048; off <<= 1) {
        int v0 = (t >= off) ? s[t - off] : 0;
        int v1 = (t + 1024 >= off) ? s[t + 1024 - off] : 0;
        __syncthreads();
        s[t] += v0;
        s[t + 1024] += v1;
        __syncthreads();
    }
    if (t == 0) offs[0] = 0;
    if (t < NN)        offs[t + 1]        = s[t];          // exclusive scan
    if (t + 1024 < NN) offs[t + 1024 + 1] = s[t + 1024];
}

__global__ void k_fill(const int* __restrict__ src, const int* __restrict__ dst,
                       const float* __restrict__ dinv, const int* __restrict__ offs,
                       int* __restrict__ cursor, float* __restrict__ wsum,
                       int2* __restrict__ csr) {
    int e = blockIdx.x * 256 + threadIdx.x;
    if (e < NE) {
        int s  = src[e];
        int dd = dst[e];
        float w = dinv[s] * dinv[dd];
        atomicAdd(&wsum[s], w);                 // out-edge contribution to wsum
        int p = offs[dd] + atomicAdd(&cursor[dd], 1);
        csr[p] = make_int2(s, __float_as_int(w));
    }
}

// ---- fused: gather 32-node tile -> LDS, GEMM vs W1, relu, wsum-weighted reduce ----
// G[n,:] = dinv[n]^2 * X[b,n,:] + sum_{e: dst=n} w_e * X[b,src_e,:]  (into LDS)
// x1 = relu(G @ W1 + b1);  y[b,:] += sum_n wsum[n] * x1[b,n,:]
__global__ __launch_bounds__(128) void k_fused(const float* __restrict__ X,
                                               const int* __restrict__ offs,
                                               const int2* __restrict__ csr,
                                               const float* __restrict__ dinv,
                                               const float* __restrict__ W1,
                                               const float* __restrict__ b1,
                                               const float* __restrict__ wsum,
                                               float* __restrict__ y) {
    __shared__ float As[128 * 36];   // A^T: As[k][r], stride 36 (16B-aligned rows)
    __shared__ float yred[128];
    const int tid = threadIdx.x;

    // XCD batch-partition swizzle: linear block id round-robins over 8 XCDs;
    // give each XCD a contiguous group of 4 batches so its L2 only ever sees
    // ~4 MB of X. grid.x == NXCD * BPX * NCHUNK == 2016 exactly.
    const int L     = blockIdx.x;
    const int xcd   = L & (NXCD - 1);
    const int slot  = L >> 3;               // 0 .. BPX*NCHUNK-1
    const int b     = xcd * BPX + slot / NCHUNK;
    const int chunk = slot % NCHUNK;
    const int n0    = chunk * 32;

    const float* Xb = X + (size_t)b * NN * ND;

    // ---- gather phase: thread tid owns feature dim tid for all 32 tile rows ----
    #pragma unroll 2
    for (int j = 0; j < 32; j++) {
        const int n = n0 + j;
        float acc = 0.f;
        if (n < NN) {
            float di = dinv[n];
            acc = di * di * Xb[(size_t)n * ND + tid];
            int e0 = offs[n], e1 = offs[n + 1];
            #pragma unroll 4
            for (int e = e0; e < e1; e++) {
                int2 ed = csr[e];
                acc = fmaf(__int_as_float(ed.y), Xb[(size_t)ed.x * ND + tid], acc);
            }
        }
        As[tid * 36 + j] = acc;
    }
    yred[tid] = 0.f;
    __syncthreads();

    // ---- GEMM phase ----
    const int cg = tid & 31;   // col group: cols 4*cg .. 4*cg+3
    const int rg = tid >> 5;   // row group: rows 8*rg .. 8*rg+7
    float acc[8][4];
    #pragma unroll
    for (int i = 0; i < 8; i++)
        #pragma unroll
        for (int c = 0; c < 4; c++) acc[i][c] = 0.f;

    const float4* Wrow = (const float4*)W1 + cg;   // W1[k][4cg..]
    #pragma unroll 4
    for (int k = 0; k < 128; k++) {
        float4 w  = Wrow[k * 32];                         // global (L1/L2-hot)
        float4 a0 = *(const float4*)&As[k * 36 + rg * 8];
        float4 a1 = *(const float4*)&As[k * 36 + rg * 8 + 4];
        float av[8] = {a0.x, a0.y, a0.z, a0.w, a1.x, a1.y, a1.z, a1.w};
        #pragma unroll
        for (int i = 0; i < 8; i++) {
            acc[i][0] = fmaf(av[i], w.x, acc[i][0]);
            acc[i][1] = fmaf(av[i], w.y, acc[i][1]);
            acc[i][2] = fmaf(av[i], w.z, acc[i][2]);
            acc[i][3] = fmaf(av[i], w.w, acc[i][3]);
        }
    }

    // ---- epilogue: relu + weighted reduce over this block's 32 rows ----
    float4 bias = *((const float4*)b1 + cg);
    float yacc[4] = {0.f, 0.f, 0.f, 0.f};
    #pragma unroll
    for (int i = 0; i < 8; i++) {
        int n = n0 + rg * 8 + i;
        if (n < NN) {
            float wn = wsum[n];
            yacc[0] = fmaf(wn, fmaxf(acc[i][0] + bias.x, 0.f), yacc[0]);
            yacc[1] = fmaf(wn, fmaxf(acc[i][1] + bias.y, 0.f), yacc[1]);
            yacc[2] = fmaf(wn, fmaxf(acc[i][2] + bias.z, 0.f), yacc[2]);
            yacc[3] = fmaf(wn, fmaxf(acc[i][3] + bias.w, 0.f), yacc[3]);
        }
    }
    atomicAdd(&yred[4 * cg + 0], yacc[0]);
    atomicAdd(&yred[4 * cg + 1], yacc[1]);
    atomicAdd(&yred[4 * cg + 2], yacc[2]);
    atomicAdd(&yred[4 * cg + 3], yacc[3]);
    __syncthreads();
    atomicAdd(&y[b * ND + tid], yred[tid]);
}

// ---- out[b,:] = (1/N) * y[b,:] @ W2 + b2 ----
__global__ __launch_bounds__(128) void k_out(const float* __restrict__ y,
                                             const float* __restrict__ W2,
                                             const float* __restrict__ b2,
                                             float* __restrict__ out) {
    __shared__ float ys[128];
    const int b = blockIdx.x;
    const int d = threadIdx.x;
    ys[d] = y[b * ND + d] * (1.f / (float)NN);
    __syncthreads();
    float acc = b2[d];
    #pragma unroll 8
    for (int k = 0; k < 128; k++)
        acc = fmaf(ys[k], W2[k * ND + d], acc);
    out[b * ND + d] = acc;
}

extern "C" void kernel_launch(void* const* d_in, const int* in_sizes, int n_in,
                              void* d_out, int out_size, void* d_ws, size_t ws_size,
                              hipStream_t stream) {
    (void)in_sizes; (void)n_in; (void)out_size; (void)ws_size;
    const float* X   = (const float*)d_in[0];   // gene_emb [B,N,128] fp32
    const int*   src = (const int*)d_in[1];     // edge_src [E]
    const int*   dst = (const int*)d_in[2];     // edge_dst [E]
    const float* W1  = (const float*)d_in[3];
    const float* b1  = (const float*)d_in[4];
    const float* W2  = (const float*)d_in[5];
    const float* b2  = (const float*)d_in[6];
    float* out = (float*)d_out;

    char* ws = (char*)d_ws;
    int*   cnt    = (int*)  (ws + OFF_CNT);
    float* dinv   = (float*)(ws + OFF_DINV);
    float* wsum   = (float*)(ws + OFF_WSUM);
    int*   offs   = (int*)  (ws + OFF_OFFS);
    int*   cursor = (int*)  (ws + OFF_CURSOR);
    int2*  csr    = (int2*) (ws + OFF_CSR);
    float* y      = (float*)(ws + OFF_Y);

    // zero cnt/cursor/y (whole metadata region is ~0.6 MB; one memset is cheap)
    hipMemsetAsync(ws, 0, META_END, stream);

    k_deg <<<(NE + 255) / 256, 256, 0, stream>>>(dst, cnt);
    k_dinv<<<(NN + 255) / 256, 256, 0, stream>>>(cnt, dinv, wsum);
    k_scan<<<1, 1024, 0, stream>>>(cnt, offs);
    k_fill<<<(NE + 255) / 256, 256, 0, stream>>>(src, dst, dinv, offs, cursor, wsum, csr);

    k_fused<<<NXCD * BPX * NCHUNK, 128, 0, stream>>>(X, offs, csr, dinv, W1, b1, wsum, y);
    k_out<<<NB, 128, 0, stream>>>(y, W2, b2, out);
}